// Round 4
// baseline (55712.384 us; speedup 1.0000x reference)
//
#include <hip/hip_runtime.h>
#include <hip/hip_cooperative_groups.h>
#include <cmath>

namespace cg = cooperative_groups;

// RSSM scan: B=16, T=64, A=6, E=12288, DET=4096, HID=1024, S=32, D=32
// fp32 throughout (argmax stability). Deterministic fixed-order reductions.

#define B 16
#define T_STEPS 64
#define A_DIM 6
#define E_DIM 12288
#define DET 4096
#define HID 1024
#define SD 1024
#define OUT_C 8192
#define OUT_RSTRIDE (T_STEPS * OUT_C)

typedef float f2v __attribute__((ext_vector_type(2)));
typedef float f4v __attribute__((ext_vector_type(4)));

// ---------------- block reduce (deterministic), works for 256 or 1024 thr ----------------
__device__ __forceinline__ float block_sum(float v, float* red, int nw) {
#pragma unroll
  for (int m = 32; m >= 1; m >>= 1) v += __shfl_xor(v, m, 64);
  int wid = threadIdx.x >> 6;
  if ((threadIdx.x & 63) == 0) red[wid] = v;
  __syncthreads();
  if (wid == 0) {
    float s = ((int)threadIdx.x < nw) ? red[threadIdx.x] : 0.0f;
#pragma unroll
    for (int m = 8; m >= 1; m >>= 1) s += __shfl_xor(s, m, 16);
    if (threadIdx.x == 0) red[0] = s;
  }
  __syncthreads();
  float out = red[0];
  __syncthreads();
  return out;
}

__global__ __launch_bounds__(1024) void k_tanh(const float* __restrict__ w, float* __restrict__ o) {
  int i = blockIdx.x * 1024 + threadIdx.x;
  if (i < DET) o[i] = tanhf(w[i]);
}

// ---------------- prep (t=0 only) ----------------
__global__ __launch_bounds__(256) void k_prep(
    const float* __restrict__ isf, const float* __restrict__ pa, int t,
    const float* __restrict__ stoch_prev,
    const float* __restrict__ deter_prev, long deter_prev_stride,
    const float* __restrict__ init_stoch, const float* __restrict__ init_deter_row,
    float* __restrict__ stoch_in, float* __restrict__ deter_in, float* __restrict__ a_eff) {
  int r = blockIdx.x;
  float f = isf[r * T_STEPS + t];
  float omf = 1.0f - f;
  for (int c = threadIdx.x; c < SD; c += 256)
    stoch_in[r * SD + c] = stoch_prev[r * SD + c] * omf + init_stoch[r * SD + c] * f;
  for (int c = threadIdx.x; c < DET; c += 256)
    deter_in[r * DET + c] = deter_prev[(long)r * deter_prev_stride + c] * omf + init_deter_row[c] * f;
  if ((int)threadIdx.x < A_DIM) {
    float a = pa[(r * T_STEPS + t) * A_DIM + threadIdx.x];
    a = a * (1.0f / fmaxf(fabsf(a), 1.0f));
    a_eff[r * 8 + threadIdx.x] = a * omf;
  }
}

// ---------------- standalone K-split GEMM (init chain only) ----------------
struct GemmArgs {
  const float* A0; long sA0; int cA0;
  const float* A1; long sA1;
  const float* W; int N; int Ktot; int KS; int nsplit;
  float* P;
};

template <bool NT>
__global__ __launch_bounds__(256) void k_gemm(GemmArgs g) {
  if ((int)blockIdx.y >= g.nsplit) return;
  const int tid = threadIdx.x;
  const int c0 = blockIdx.x * 512 + tid * 2;
  const int k0 = (int)blockIdx.y * g.KS;
  __shared__ float in_s[16][64];
  float acc[16][2];
#pragma unroll
  for (int r = 0; r < 16; r++) { acc[r][0] = 0.f; acc[r][1] = 0.f; }
  for (int kb = 0; kb < g.KS; kb += 64) {
    const int kbase = k0 + kb;
    __syncthreads();
#pragma unroll
    for (int j = 0; j < 4; j++) {
      int ii = tid + j * 256;
      int r = ii >> 6, kk = ii & 63;
      int k = kbase + kk;
      float v = 0.f;
      if (k < g.cA0) v = g.A0[(long)r * g.sA0 + k];
      else if (k < g.Ktot) v = g.A1[(long)r * g.sA1 + (k - g.cA0)];
      in_s[r][kk] = v;
    }
    __syncthreads();
    if (kbase + 64 <= g.Ktot) {
      const float* wp = g.W + (size_t)kbase * g.N + c0;
#pragma unroll 4
      for (int kk = 0; kk < 64; kk++) {
        f2v w = NT ? __builtin_nontemporal_load((const f2v*)wp) : *(const f2v*)wp;
        wp += g.N;
#pragma unroll
        for (int r = 0; r < 16; r++) {
          acc[r][0] += in_s[r][kk] * w[0]; acc[r][1] += in_s[r][kk] * w[1];
        }
      }
    } else {
      for (int kk = 0; kk < 64; kk++) {
        int krow = kbase + kk; if (krow >= g.Ktot) krow = g.Ktot - 1;
        const f2v w = *(const f2v*)(g.W + (size_t)krow * g.N + c0);
#pragma unroll
        for (int r = 0; r < 16; r++) {
          acc[r][0] += in_s[r][kk] * w[0]; acc[r][1] += in_s[r][kk] * w[1];
        }
      }
    }
  }
#pragma unroll
  for (int r = 0; r < 16; r++)
    *(f2v*)(g.P + ((size_t)blockIdx.y * 16 + r) * g.N + c0) = f2v{acc[r][0], acc[r][1]};
}

// ---------------- init finish: sum partials + LN + silu (1024 thr) ----------------
__global__ __launch_bounds__(1024) void k_fin_init(
    const float* __restrict__ P, int nP, const float* __restrict__ gv,
    const float* __restrict__ bv, float* __restrict__ o) {
  int r = blockIdx.x, c = threadIdx.x;
  __shared__ float red[18];
  float v = 0.f;
  for (int ks = 0; ks < nP; ks++) v += P[((size_t)ks * 16 + r) * HID + c];
  float m = block_sum(v, red, 16) * (1.0f / (float)HID);
  float d = v - m;
  float var = block_sum(d * d, red, 16) * (1.0f / (float)HID);
  float rs = 1.0f / sqrtf(var + 1e-3f);
  float y = d * rs * gv[c] + bv[c];
  float s = 1.0f / (1.0f + expf(-y));
  o[r * HID + c] = y * s;
}

// ---------------- init sample (mode): partials+bias -> mix-softmax -> ST ----------------
__global__ __launch_bounds__(1024) void k_samp_init(
    const float* __restrict__ P, int nP, const float* __restrict__ bb,
    float* __restrict__ st) {
  int r = blockIdx.x, c = threadIdx.x;
  float acc = bb[c];
  for (int ks = 0; ks < nP; ks++) acc += P[((size_t)ks * 16 + r) * SD + c];
  int d = c & 31;
  float mx = acc;
#pragma unroll
  for (int m = 16; m >= 1; m >>= 1) mx = fmaxf(mx, __shfl_xor(mx, m, 32));
  float e = expf(acc - mx);
  float se = e;
#pragma unroll
  for (int m = 16; m >= 1; m >>= 1) se += __shfl_xor(se, m, 32);
  float p = 0.99f * (e / se) + 3.125e-4f;
  float y = p;  // mode: argmax over p
  float by = y; int bi = d;
#pragma unroll
  for (int m = 16; m >= 1; m >>= 1) {
    float oy = __shfl_xor(by, m, 32);
    int oi = __shfl_xor(bi, m, 32);
    if (oy > by || (oy == by && oi < bi)) { by = oy; bi = oi; }
  }
  float oh = (d == bi) ? 1.0f : 0.0f;
  st[r * SD + c] = (oh + p) - p;
}

// ---------------- generalized tiled GEMM: out[M x 1024] = A[M x K] @ Bw[K x 1024] (+bias)
// 64x64 tiles, 4x4 micro, 256 thr, grid (16, M/64).
__global__ __launch_bounds__(256) void k_mm(const float* __restrict__ A, long lda,
                                            const float* __restrict__ Bw, int K,
                                            float* __restrict__ out, long ldo,
                                            const float* __restrict__ bias) {
  __shared__ float As[32][68];
  __shared__ float Bs[32][68];
  const int tid = threadIdx.x;
  const int tx = tid & 15, ty = tid >> 4;
  const int row0 = blockIdx.y * 64, col0 = blockIdx.x * 64;
  const int ar = tid >> 2, ak = (tid & 3) * 8;
  const int bk = tid >> 4, bc = (tid & 15) * 4;
  float acc[4][4] = {};
  const float* ap = A + (size_t)(row0 + ar) * lda + ak;
  const float* bp = Bw + (size_t)bk * HID + col0 + bc;
  for (int k0 = 0; k0 < K; k0 += 32) {
    float4 a0 = *(const float4*)(ap + k0);
    float4 a1 = *(const float4*)(ap + k0 + 4);
    float4 b0 = *(const float4*)(bp + (size_t)k0 * HID);
    float4 b1 = *(const float4*)(bp + (size_t)(k0 + 16) * HID);
    __syncthreads();
    As[ak + 0][ar] = a0.x; As[ak + 1][ar] = a0.y; As[ak + 2][ar] = a0.z; As[ak + 3][ar] = a0.w;
    As[ak + 4][ar] = a1.x; As[ak + 5][ar] = a1.y; As[ak + 6][ar] = a1.z; As[ak + 7][ar] = a1.w;
    *(float4*)&Bs[bk][bc] = b0;
    *(float4*)&Bs[bk + 16][bc] = b1;
    __syncthreads();
#pragma unroll
    for (int kk = 0; kk < 32; kk++) {
      float4 av = *(const float4*)&As[kk][ty * 4];
      float4 bv = *(const float4*)&Bs[kk][tx * 4];
      acc[0][0] += av.x * bv.x; acc[0][1] += av.x * bv.y; acc[0][2] += av.x * bv.z; acc[0][3] += av.x * bv.w;
      acc[1][0] += av.y * bv.x; acc[1][1] += av.y * bv.y; acc[1][2] += av.y * bv.z; acc[1][3] += av.y * bv.w;
      acc[2][0] += av.z * bv.x; acc[2][1] += av.z * bv.y; acc[2][2] += av.z * bv.z; acc[2][3] += av.z * bv.w;
      acc[3][0] += av.w * bv.x; acc[3][1] += av.w * bv.y; acc[3][2] += av.w * bv.z; acc[3][3] += av.w * bv.w;
    }
  }
#pragma unroll
  for (int i = 0; i < 4; i++) {
    float4 o;
    int col = col0 + tx * 4;
    o.x = acc[i][0] + (bias ? bias[col + 0] : 0.f);
    o.y = acc[i][1] + (bias ? bias[col + 1] : 0.f);
    o.z = acc[i][2] + (bias ? bias[col + 2] : 0.f);
    o.w = acc[i][3] + (bias ? bias[col + 3] : 0.f);
    *(float4*)(out + (size_t)(row0 + ty * 4 + i) * ldo + col) = o;
  }
}

// ---------------- deferred: per-row LN + silu in place ----------------
__global__ __launch_bounds__(256) void k_ln_rows(float* __restrict__ h,
                                                 const float* __restrict__ gv,
                                                 const float* __restrict__ bv) {
  int row = blockIdx.x, c0 = threadIdx.x * 4;
  __shared__ float red[18];
  float4 v = *(const float4*)(h + (size_t)row * HID + c0);
  float lsum = (v.x + v.y) + (v.z + v.w);
  float m = block_sum(lsum, red, 4) * (1.0f / (float)HID);
  float dx = v.x - m, dy = v.y - m, dz = v.z - m, dw = v.w - m;
  float lv = (dx * dx + dy * dy) + (dz * dz + dw * dw);
  float var = block_sum(lv, red, 4) * (1.0f / (float)HID);
  float rs = 1.0f / sqrtf(var + 1e-3f);
  float4 o;
  float y0 = dx * rs * gv[c0] + bv[c0];         o.x = y0 / (1.0f + expf(-y0));
  float y1 = dy * rs * gv[c0 + 1] + bv[c0 + 1]; o.y = y1 / (1.0f + expf(-y1));
  float y2 = dz * rs * gv[c0 + 2] + bv[c0 + 2]; o.z = y2 / (1.0f + expf(-y2));
  float y3 = dw * rs * gv[c0 + 3] + bv[c0 + 3]; o.w = y3 / (1.0f + expf(-y3));
  *(float4*)(h + (size_t)row * HID + c0) = o;
}

// ---------------- deferred: batched prior sample (logits already in out+7168) ----------
__global__ __launch_bounds__(1024) void k_samp_prior(float* __restrict__ out,
                                                     const float* __restrict__ gum) {
  int m = blockIdx.x, c = threadIdx.x;
  float lp = out[(size_t)m * OUT_C + 7168 + c];
  int d = c & 31;
  float mx = lp;
#pragma unroll
  for (int mm = 16; mm >= 1; mm >>= 1) mx = fmaxf(mx, __shfl_xor(mx, mm, 32));
  float e = expf(lp - mx);
  float se = e;
#pragma unroll
  for (int mm = 16; mm >= 1; mm >>= 1) se += __shfl_xor(se, mm, 32);
  float p = 0.99f * (e / se) + 3.125e-4f;
  float y = logf(p) + gum[(size_t)m * SD + c];
  float by = y; int bi = d;
#pragma unroll
  for (int mm = 16; mm >= 1; mm >>= 1) {
    float oy = __shfl_xor(by, mm, 32);
    int oi = __shfl_xor(bi, mm, 32);
    if (oy > by || (oy == by && oi < bi)) { by = oy; bi = oi; }
  }
  float oh = (d == bi) ? 1.0f : 0.0f;
  out[(size_t)m * OUT_C + 6144 + c] = (oh + p) - p;
}

// ================= cooperative scan kernel =================
struct ScanArgs {
  const float *isf, *pa, *gpost;
  const float *W1, *g1, *b1, *Wg, *gg, *bg, *Wo2, *go, *bo, *Wob, *bbo;
  const float *init_stoch, *init_deter;
  float* out;
  float *Pg, *Sg, *red_s, *red_q, *Pimg1, *Pb, *Ps1;
  float *stoch_in, *deter_in, *deter_new, *a_eff, *x, *h2;
};

template <bool NT>
__device__ __forceinline__ void gemm_part2(
    const float* __restrict__ A0, int sA0, int cA0,
    const float* __restrict__ A1, int sA1,
    const float* __restrict__ W, int N, int Ktot,
    int k0, int KS, int c0, float* __restrict__ Pout,
    int tid, float (*in_s)[64]) {
  float acc[16][2] = {};
  for (int kb = 0; kb < KS; kb += 64) {
    const int kbase = k0 + kb;
    __syncthreads();
#pragma unroll
    for (int j = 0; j < 4; j++) {
      int ii = tid + j * 256;
      int r = ii >> 6, kk = ii & 63;
      int k = kbase + kk;
      float v = 0.f;
      if (k < cA0) v = A0[(long)r * sA0 + k];
      else if (k < Ktot) v = A1[(long)r * sA1 + (k - cA0)];
      in_s[r][kk] = v;
    }
    __syncthreads();
    if (kbase + 64 <= Ktot) {
      const float* wp = W + (size_t)kbase * N + c0;
#pragma unroll 8
      for (int kk = 0; kk < 64; kk++) {
        f2v w = NT ? __builtin_nontemporal_load((const f2v*)wp) : *(const f2v*)wp;
        wp += N;
#pragma unroll
        for (int r = 0; r < 16; r++) {
          acc[r][0] += in_s[r][kk] * w[0]; acc[r][1] += in_s[r][kk] * w[1];
        }
      }
    } else {
      for (int kk = 0; kk < 64; kk++) {
        int krow = kbase + kk; if (krow >= Ktot) krow = Ktot - 1;
        const f2v w = *(const f2v*)(W + (size_t)krow * N + c0);
#pragma unroll
        for (int r = 0; r < 16; r++) {
          acc[r][0] += in_s[r][kk] * w[0]; acc[r][1] += in_s[r][kk] * w[1];
        }
      }
    }
  }
#pragma unroll
  for (int r = 0; r < 16; r++)
    *(f2v*)(Pout + (size_t)r * N + c0) = f2v{acc[r][0], acc[r][1]};
}

__device__ __forceinline__ void gemm_part4(
    const float* __restrict__ A0, int sA0, int cA0,
    const float* __restrict__ A1, int sA1,
    const float* __restrict__ W, int N,
    int k0, int KS, int c0, float* __restrict__ Pout,
    int tid, float (*in_s)[64]) {
  float acc[16][4] = {};
  for (int kb = 0; kb < KS; kb += 64) {
    const int kbase = k0 + kb;
    __syncthreads();
#pragma unroll
    for (int j = 0; j < 4; j++) {
      int ii = tid + j * 256;
      int r = ii >> 6, kk = ii & 63;
      int k = kbase + kk;
      float v = (k < cA0) ? A0[(long)r * sA0 + k] : A1[(long)r * sA1 + (k - cA0)];
      in_s[r][kk] = v;
    }
    __syncthreads();
    const float* wp = W + (size_t)kbase * N + c0;
#pragma unroll 8
    for (int kk = 0; kk < 64; kk++) {
      f4v w = *(const f4v*)wp;
      wp += N;
#pragma unroll
      for (int r = 0; r < 16; r++) {
        float iv = in_s[r][kk];
        acc[r][0] += iv * w[0]; acc[r][1] += iv * w[1];
        acc[r][2] += iv * w[2]; acc[r][3] += iv * w[3];
      }
    }
  }
#pragma unroll
  for (int r = 0; r < 16; r++)
    *(f4v*)(Pout + (size_t)r * N + c0) = f4v{acc[r][0], acc[r][1], acc[r][2], acc[r][3]};
}

__global__ __launch_bounds__(256, 4) void k_scan(ScanArgs a) {
  cg::grid_group grid = cg::this_grid();
  const int NB = gridDim.x, bid = blockIdx.x, tid = threadIdx.x;
  __shared__ float in_s[16][64];
  __shared__ float red[18];
  __shared__ float mv[2];
  __shared__ float rbuf[8];

  for (int t = 0; t < T_STEPS; t++) {
    // ---- A: img1 partials (K=1030, KS=64, 17 splits x 2 tiles = 34 items) ----
    for (int w = bid; w < 34; w += NB) {
      int split = w >> 1, tile = w & 1;
      gemm_part2<true>(a.stoch_in, SD, SD, a.a_eff, 8, a.W1, HID, SD + A_DIM,
                       split * 64, 64, tile * 512 + tid * 2,
                       a.Pimg1 + (size_t)split * 16 * HID, tid, in_s);
    }
    grid.sync();
    // ---- B: img1 finish -> x (16 items) ----
    for (int w = bid; w < 16; w += NB) {
      int r = w, c0 = tid * 4;
      float v[4] = {};
      for (int ks = 0; ks < 17; ks++) {
        f4v pv = *(const f4v*)(a.Pimg1 + ((size_t)ks * 16 + r) * HID + c0);
        v[0] += pv[0]; v[1] += pv[1]; v[2] += pv[2]; v[3] += pv[3];
      }
      float lsum = (v[0] + v[1]) + (v[2] + v[3]);
      float m = block_sum(lsum, red, 4) * (1.0f / (float)HID);
      float d0 = v[0] - m, d1 = v[1] - m, d2 = v[2] - m, d3 = v[3] - m;
      float lv = (d0 * d0 + d1 * d1) + (d2 * d2 + d3 * d3);
      float var = block_sum(lv, red, 4) * (1.0f / (float)HID);
      float rs = 1.0f / sqrtf(var + 1e-3f);
      f4v o;
      float dd[4] = {d0, d1, d2, d3};
#pragma unroll
      for (int j = 0; j < 4; j++) {
        float y = dd[j] * rs * a.g1[c0 + j] + a.b1[c0 + j];
        o[j] = y / (1.0f + expf(-y));
      }
      *(f4v*)(a.x + (size_t)r * HID + c0) = o;
    }
    grid.sync();
    // ---- C: GRU partials (K=5120, KS=256, 20 splits x 12 tiles = 240 items) ----
    for (int w = bid; w < 240; w += NB) {
      int split = w / 12, tile = w % 12;
      gemm_part4(a.x, HID, HID, a.deter_in, DET, a.Wg, 3 * DET,
                 split * 256, 256, tile * 1024 + tid * 4,
                 a.Pg + (size_t)split * 16 * 3 * DET, tid, in_s);
    }
    grid.sync();
    // ---- D: red (12 chunks x 16 rows = 192 items) ----
    for (int w = bid; w < 192; w += NB) {
      int chunk = w % 12, r = w / 12;
      int c = chunk * 1024 + tid * 4;
      f4v s = {0, 0, 0, 0};
      for (int ks = 0; ks < 20; ks++) {
        f4v v = *(const f4v*)(a.Pg + ((size_t)ks * 16 + r) * (3 * DET) + c);
        s[0] += v[0]; s[1] += v[1]; s[2] += v[2]; s[3] += v[3];
      }
      *(f4v*)(a.Sg + (size_t)r * (3 * DET) + c) = s;
      float sx = (s[0] + s[1]) + (s[2] + s[3]);
      float sq = (s[0] * s[0] + s[1] * s[1]) + (s[2] * s[2] + s[3] * s[3]);
#pragma unroll
      for (int m = 32; m >= 1; m >>= 1) { sx += __shfl_xor(sx, m, 64); sq += __shfl_xor(sq, m, 64); }
      int wid = tid >> 6;
      if ((tid & 63) == 0) { rbuf[wid] = sx; rbuf[4 + wid] = sq; }
      __syncthreads();
      if (tid == 0) {
        a.red_s[r * 12 + chunk] = (rbuf[0] + rbuf[1]) + (rbuf[2] + rbuf[3]);
        a.red_q[r * 12 + chunk] = (rbuf[4] + rbuf[5]) + (rbuf[6] + rbuf[7]);
      }
      __syncthreads();
    }
    grid.sync();
    // ---- E: gate (16 rows x 4 quarters = 64 items) ----
    for (int w = bid; w < 64; w += NB) {
      int r = w >> 2, q = w & 3;
      if (tid == 0) {
        float s = 0.f, qq = 0.f;
        for (int k2 = 0; k2 < 12; k2++) { s += a.red_s[r * 12 + k2]; qq += a.red_q[r * 12 + k2]; }
        float m = s * (1.0f / (float)(3 * DET));
        float var = qq * (1.0f / (float)(3 * DET)) - m * m;
        mv[0] = m; mv[1] = 1.0f / sqrtf(var + 1e-3f);
      }
      __syncthreads();
      float m = mv[0], rs = mv[1];
      float ft = (t + 1 < T_STEPS) ? a.isf[r * T_STEPS + t + 1] : 0.0f;
      int j0 = q * 1024 + tid * 4;
      const float* Sr = a.Sg + (size_t)r * (3 * DET);
      f4v lrv = *(const f4v*)(Sr + j0);
      f4v lcv = *(const f4v*)(Sr + j0 + DET);
      f4v luv = *(const f4v*)(Sr + j0 + 2 * DET);
      f4v dn, din;
#pragma unroll
      for (int j = 0; j < 4; j++) {
        int jj = j0 + j;
        float lr = (lrv[j] - m) * rs * a.gg[jj] + a.bg[jj];
        float lc = (lcv[j] - m) * rs * a.gg[jj + DET] + a.bg[jj + DET];
        float lu = (luv[j] - m) * rs * a.gg[jj + 2 * DET] + a.bg[jj + 2 * DET];
        float rr = 1.0f / (1.0f + expf(-lr));
        float cd = tanhf(rr * lc);
        float uu = 1.0f / (1.0f + expf(-(lu - 1.0f)));
        float d = uu * cd + (1.0f - uu) * a.deter_in[(size_t)r * DET + jj];
        dn[j] = d;
        din[j] = d * (1.0f - ft) + a.init_deter[jj] * ft;
      }
      *(f4v*)(a.deter_new + (size_t)r * DET + j0) = dn;
      *(f4v*)(a.out + (size_t)(r * T_STEPS + t) * OUT_C + 1024 + j0) = dn;
      __syncthreads();
      *(f4v*)(a.deter_in + (size_t)r * DET + j0) = din;
    }
    grid.sync();
    // ---- F: obs-deter partials (K=4096, KS=128, 32 splits x 2 tiles = 64 items) ----
    for (int w = bid; w < 64; w += NB) {
      int split = w >> 1, tile = w & 1;
      gemm_part2<true>(a.deter_new, DET, DET, nullptr, 0, a.Wo2, HID, DET,
                       split * 128, 128, tile * 512 + tid * 2,
                       a.Pb + (size_t)split * 16 * HID, tid, in_s);
    }
    grid.sync();
    // ---- G: obs finish (+OE) -> h2 (16 items) ----
    for (int w = bid; w < 16; w += NB) {
      int r = w, c0 = tid * 4;
      f4v oe = *(const f4v*)(a.out + (size_t)(r * T_STEPS + t) * OUT_C + 5120 + c0);
      float v[4] = {oe[0], oe[1], oe[2], oe[3]};
      for (int ks = 0; ks < 32; ks++) {
        f4v pv = *(const f4v*)(a.Pb + ((size_t)ks * 16 + r) * HID + c0);
        v[0] += pv[0]; v[1] += pv[1]; v[2] += pv[2]; v[3] += pv[3];
      }
      float lsum = (v[0] + v[1]) + (v[2] + v[3]);
      float m = block_sum(lsum, red, 4) * (1.0f / (float)HID);
      float d0 = v[0] - m, d1 = v[1] - m, d2 = v[2] - m, d3 = v[3] - m;
      float lv = (d0 * d0 + d1 * d1) + (d2 * d2 + d3 * d3);
      float var = block_sum(lv, red, 4) * (1.0f / (float)HID);
      float rs = 1.0f / sqrtf(var + 1e-3f);
      float dd[4] = {d0, d1, d2, d3};
      f4v o;
#pragma unroll
      for (int j = 0; j < 4; j++) {
        float y = dd[j] * rs * a.go[c0 + j] + a.bo[c0 + j];
        o[j] = y / (1.0f + expf(-y));
      }
      *(f4v*)(a.h2 + (size_t)r * HID + c0) = o;
    }
    grid.sync();
    // ---- H: post-sample partials (K=1024, KS=64, 16 splits x 2 tiles = 32 items) ----
    for (int w = bid; w < 32; w += NB) {
      int split = w >> 1, tile = w & 1;
      gemm_part2<true>(a.h2, HID, HID, nullptr, 0, a.Wob, SD, HID,
                       split * 64, 64, tile * 512 + tid * 2,
                       a.Ps1 + (size_t)split * 16 * SD, tid, in_s);
    }
    grid.sync();
    // ---- I: post sample + next-step blends (16 items) ----
    for (int w = bid; w < 16; w += NB) {
      int r = w, c0 = tid * 4;
      float acc[4];
#pragma unroll
      for (int j = 0; j < 4; j++) acc[j] = a.bbo[c0 + j];
      for (int ks = 0; ks < 16; ks++) {
        f4v pv = *(const f4v*)(a.Ps1 + ((size_t)ks * 16 + r) * SD + c0);
        acc[0] += pv[0]; acc[1] += pv[1]; acc[2] += pv[2]; acc[3] += pv[3];
      }
      float mx = fmaxf(fmaxf(acc[0], acc[1]), fmaxf(acc[2], acc[3]));
#pragma unroll
      for (int mm = 1; mm <= 4; mm <<= 1) mx = fmaxf(mx, __shfl_xor(mx, mm, 64));
      float e[4], p[4], y[4];
      float se = 0.f;
#pragma unroll
      for (int j = 0; j < 4; j++) { e[j] = expf(acc[j] - mx); }
      se = (e[0] + e[1]) + (e[2] + e[3]);
#pragma unroll
      for (int mm = 1; mm <= 4; mm <<= 1) se += __shfl_xor(se, mm, 64);
      const float* gp = a.gpost + (size_t)(r * T_STEPS + t) * SD + c0;
#pragma unroll
      for (int j = 0; j < 4; j++) {
        p[j] = 0.99f * (e[j] / se) + 3.125e-4f;
        y[j] = logf(p[j]) + gp[j];
      }
      int dbase = (tid & 7) * 4;
      float by = y[0]; int bi = dbase;
#pragma unroll
      for (int j = 1; j < 4; j++) { if (y[j] > by) { by = y[j]; bi = dbase + j; } }
#pragma unroll
      for (int mm = 1; mm <= 4; mm <<= 1) {
        float oy = __shfl_xor(by, mm, 64);
        int oi = __shfl_xor(bi, mm, 64);
        if (oy > by || (oy == by && oi < bi)) { by = oy; bi = oi; }
      }
      f4v ost, olg, nst;
      float fn = (t + 1 < T_STEPS) ? a.isf[r * T_STEPS + t + 1] : 0.0f;
#pragma unroll
      for (int j = 0; j < 4; j++) {
        float oh = ((dbase + j) == bi) ? 1.0f : 0.0f;
        float outv = (oh + p[j]) - p[j];
        ost[j] = outv;
        olg[j] = acc[j];
        nst[j] = outv * (1.0f - fn) + a.init_stoch[(size_t)r * SD + c0 + j] * fn;
      }
      float* ob = a.out + (size_t)(r * T_STEPS + t) * OUT_C;
      *(f4v*)(ob + c0) = ost;
      *(f4v*)(ob + 5120 + c0) = olg;
      *(f4v*)(a.stoch_in + (size_t)r * SD + c0) = nst;
      if (c0 < 8) {
#pragma unroll
        for (int j = 0; j < 4; j++) {
          int c = c0 + j;
          if (c < A_DIM) {
            float av = (t + 1 < T_STEPS) ? a.pa[(r * T_STEPS + t + 1) * A_DIM + c] : 0.0f;
            av = av * (1.0f / fmaxf(fabsf(av), 1.0f));
            a.a_eff[r * 8 + c] = av * (1.0f - fn);
          }
        }
      }
    }
    grid.sync();
  }
}

// ---------------- host ----------------
extern "C" void kernel_launch(void* const* d_in, const int* in_sizes, int n_in,
                              void* d_out, int out_size, void* d_ws, size_t ws_size,
                              hipStream_t stream) {
  const float* embed  = (const float*)d_in[0];
  const float* pa     = (const float*)d_in[1];
  const float* isf    = (const float*)d_in[2];
  const float* gprior = (const float*)d_in[3];
  const float* gpost  = (const float*)d_in[4];
  const float* w_init = (const float*)d_in[5];
  const float* W1  = (const float*)d_in[6];
  const float* g1  = (const float*)d_in[7];
  const float* b1  = (const float*)d_in[8];
  const float* Wg  = (const float*)d_in[9];
  const float* gg  = (const float*)d_in[10];
  const float* bg  = (const float*)d_in[11];
  const float* W2a = (const float*)d_in[12];
  const float* g2  = (const float*)d_in[13];
  const float* b2  = (const float*)d_in[14];
  const float* W2b = (const float*)d_in[15];
  const float* bb2 = (const float*)d_in[16];
  const float* Wo  = (const float*)d_in[17];
  const float* go  = (const float*)d_in[18];
  const float* bo  = (const float*)d_in[19];
  const float* Wob = (const float*)d_in[20];
  const float* bbo = (const float*)d_in[21];
  float* out = (float*)d_out;
  float* ws  = (float*)d_ws;

  // workspace (floats)
  float* Pg    = ws;                    // 20*16*12288 = 3,932,160 (aliased as h_all after loop)
  float* h_all = Pg;                    // 1024*1024 deferred
  float* Sg    = Pg + 3932160;          // 196,608
  float* red_s = Sg + 196608;           // 192
  float* red_q = red_s + 192;           // 192
  float* Pimg1 = red_s + 512;           // 17*16*1024 = 278,528
  float* Pb    = Pimg1 + 278528;        // 32*16*1024 = 524,288 (also init Pa)
  float* Ps1   = Pb + 524288;           // 16*16*1024 = 262,144 (also init Ps0)
  float* st_   = Ps1 + 262144;
  float* init_stoch = st_;              // 16,384
  float* init_deter = st_ + 16384;      // 4,096
  float* stoch_in   = st_ + 20480;      // 16,384
  float* deter_in   = st_ + 36864;      // 65,536
  float* deter_new  = st_ + 102400;     // 65,536
  float* a_eff      = st_ + 167936;     // 128
  float* x          = st_ + 168064;     // 16,384  (also init h)
  float* h2         = st_ + 184448;     // 16,384

  // ---- OE precompute: e @ Wo[0:E] -> out post-logit slots (consumed by G, overwritten by I)
  k_mm<<<dim3(16, 16), 256, 0, stream>>>(embed, E_DIM, Wo, E_DIM, out + 5120, OUT_C, nullptr);

  // ---- init: init_deter = tanh(w_init); init_stoch = st_mode(prior_logits(init_deter))
  k_tanh<<<4, 1024, 0, stream>>>(w_init, init_deter);
  {
    GemmArgs g; g.A0 = init_deter; g.sA0 = 0; g.cA0 = DET; g.A1 = nullptr; g.sA1 = 0;
    g.W = W2a; g.N = HID; g.Ktot = DET; g.KS = 128; g.nsplit = 32; g.P = Pb;
    k_gemm<true><<<dim3(2, 32), 256, 0, stream>>>(g);
  }
  k_fin_init<<<16, 1024, 0, stream>>>(Pb, 32, g2, b2, x);
  {
    GemmArgs g; g.A0 = x; g.sA0 = HID; g.cA0 = HID; g.A1 = nullptr; g.sA1 = 0;
    g.W = W2b; g.N = SD; g.Ktot = HID; g.KS = 64; g.nsplit = 16; g.P = Ps1;
    k_gemm<true><<<dim3(2, 16), 256, 0, stream>>>(g);
  }
  k_samp_init<<<16, 1024, 0, stream>>>(Ps1, 16, bb2, init_stoch);

  // ---- t=0 prep (f[:,0]==1 -> all init) ----
  k_prep<<<16, 256, 0, stream>>>(isf, pa, 0, init_stoch, init_deter, 0,
                                 init_stoch, init_deter, stoch_in, deter_in, a_eff);

  // ---- cooperative scan ----
  ScanArgs sa;
  sa.isf = isf; sa.pa = pa; sa.gpost = gpost;
  sa.W1 = W1; sa.g1 = g1; sa.b1 = b1;
  sa.Wg = Wg; sa.gg = gg; sa.bg = bg;
  sa.Wo2 = Wo + (size_t)E_DIM * HID; sa.go = go; sa.bo = bo;
  sa.Wob = Wob; sa.bbo = bbo;
  sa.init_stoch = init_stoch; sa.init_deter = init_deter;
  sa.out = out;
  sa.Pg = Pg; sa.Sg = Sg; sa.red_s = red_s; sa.red_q = red_q;
  sa.Pimg1 = Pimg1; sa.Pb = Pb; sa.Ps1 = Ps1;
  sa.stoch_in = stoch_in; sa.deter_in = deter_in; sa.deter_new = deter_new;
  sa.a_eff = a_eff; sa.x = x; sa.h2 = h2;

  int occ = 0;
  hipOccupancyMaxActiveBlocksPerMultiprocessor(&occ, k_scan, 256, 0);
  if (occ < 1) occ = 1;
  int NB = occ * 256;
  if (NB > 1024) NB = 1024;
  void* kargs[] = {(void*)&sa};
  hipLaunchCooperativeKernel(k_scan, dim3(NB), dim3(256), kargs, 0, stream);

  // ---- deferred prior branch (batched over all (b,t)) ----
  k_mm<<<dim3(16, 16), 256, 0, stream>>>(out + 1024, OUT_C, W2a, DET, h_all, HID, nullptr);
  k_ln_rows<<<1024, 256, 0, stream>>>(h_all, g2, b2);
  k_mm<<<dim3(16, 16), 256, 0, stream>>>(h_all, HID, W2b, HID, out + 7168, OUT_C, bb2);
  k_samp_prior<<<1024, 1024, 0, stream>>>(out, gprior);
}

// Round 5
// 18834.886 us; speedup vs baseline: 2.9579x; 2.9579x over previous
//
#include <hip/hip_runtime.h>
#include <cmath>

// RSSM scan: B=16, T=64, A=6, E=12288, DET=4096, HID=1024, S=32, D=32
// fp32 throughout (argmax stability). Deterministic fixed-order reductions.
// Multi-kernel (no cooperative launch: grid.sync measured ~150us on MI355X).

#define B 16
#define T_STEPS 64
#define A_DIM 6
#define E_DIM 12288
#define DET 4096
#define HID 1024
#define SD 1024
#define OUT_C 8192
#define OUT_RSTRIDE (T_STEPS * OUT_C)

typedef float f2v __attribute__((ext_vector_type(2)));
typedef float f4v __attribute__((ext_vector_type(4)));

// ---------------- block reduce (deterministic) ----------------
__device__ __forceinline__ float block_sum(float v, float* red, int nw) {
#pragma unroll
  for (int m = 32; m >= 1; m >>= 1) v += __shfl_xor(v, m, 64);
  int wid = threadIdx.x >> 6;
  if ((threadIdx.x & 63) == 0) red[wid] = v;
  __syncthreads();
  if (wid == 0) {
    float s = ((int)threadIdx.x < nw) ? red[threadIdx.x] : 0.0f;
#pragma unroll
    for (int m = 8; m >= 1; m >>= 1) s += __shfl_xor(s, m, 16);
    if (threadIdx.x == 0) red[0] = s;
  }
  __syncthreads();
  float out = red[0];
  __syncthreads();
  return out;
}

__global__ __launch_bounds__(1024) void k_tanh(const float* __restrict__ w, float* __restrict__ o) {
  int i = blockIdx.x * 1024 + threadIdx.x;
  if (i < DET) o[i] = tanhf(w[i]);
}

// ---------------- prep (t=0 only) ----------------
__global__ __launch_bounds__(256) void k_prep(
    const float* __restrict__ isf, const float* __restrict__ pa, int t,
    const float* __restrict__ stoch_prev,
    const float* __restrict__ deter_prev, long deter_prev_stride,
    const float* __restrict__ init_stoch, const float* __restrict__ init_deter_row,
    float* __restrict__ stoch_in, float* __restrict__ deter_in, float* __restrict__ a_eff) {
  int r = blockIdx.x;
  float f = isf[r * T_STEPS + t];
  float omf = 1.0f - f;
  for (int c = threadIdx.x; c < SD; c += 256)
    stoch_in[r * SD + c] = stoch_prev[r * SD + c] * omf + init_stoch[r * SD + c] * f;
  for (int c = threadIdx.x; c < DET; c += 256)
    deter_in[r * DET + c] = deter_prev[(long)r * deter_prev_stride + c] * omf + init_deter_row[c] * f;
  if ((int)threadIdx.x < A_DIM) {
    float a = pa[(r * T_STEPS + t) * A_DIM + threadIdx.x];
    a = a * (1.0f / fmaxf(fabsf(a), 1.0f));
    a_eff[r * 8 + threadIdx.x] = a * omf;
  }
}

// ---------------- K-split GEMM: P[split][16][N] partials ----------------
struct GemmArgs {
  const float* A0; long sA0; int cA0;
  const float* A1; long sA1;
  const float* W; int N; int Ktot; int KS; int nsplit;
  float* P;
};

template <bool NT>
__global__ __launch_bounds__(256) void k_gemm(GemmArgs g) {
  const int tid = threadIdx.x;
  const int c0 = blockIdx.x * 512 + tid * 2;
  const int k0 = (int)blockIdx.y * g.KS;
  __shared__ float in_s[16][64];
  float acc[16][2];
#pragma unroll
  for (int r = 0; r < 16; r++) { acc[r][0] = 0.f; acc[r][1] = 0.f; }
  for (int kb = 0; kb < g.KS; kb += 64) {
    const int kbase = k0 + kb;
    __syncthreads();
#pragma unroll
    for (int j = 0; j < 4; j++) {
      int ii = tid + j * 256;
      int r = ii >> 6, kk = ii & 63;
      int k = kbase + kk;
      float v = 0.f;
      if (k < g.cA0) v = g.A0[(long)r * g.sA0 + k];
      else if (k < g.Ktot) v = g.A1[(long)r * g.sA1 + (k - g.cA0)];
      in_s[r][kk] = v;
    }
    __syncthreads();
    if (kbase + 64 <= g.Ktot) {
      const float* wp = g.W + (size_t)kbase * g.N + c0;
#pragma unroll 8
      for (int kk = 0; kk < 64; kk++) {
        f2v w = NT ? __builtin_nontemporal_load((const f2v*)wp) : *(const f2v*)wp;
        wp += g.N;
#pragma unroll
        for (int r = 0; r < 16; r++) {
          acc[r][0] += in_s[r][kk] * w[0]; acc[r][1] += in_s[r][kk] * w[1];
        }
      }
    } else {  // K tail (img1: Ktot=1030)
      for (int kk = 0; kk < 64; kk++) {
        int krow = kbase + kk; if (krow >= g.Ktot) krow = g.Ktot - 1;
        const f2v w = *(const f2v*)(g.W + (size_t)krow * g.N + c0);
#pragma unroll
        for (int r = 0; r < 16; r++) {
          acc[r][0] += in_s[r][kk] * w[0]; acc[r][1] += in_s[r][kk] * w[1];
        }
      }
    }
  }
#pragma unroll
  for (int r = 0; r < 16; r++)
    *(f2v*)(g.P + ((size_t)blockIdx.y * 16 + r) * g.N + c0) = f2v{acc[r][0], acc[r][1]};
}

// ---------------- finish: (optional add) + sum partials + LN + silu ----------------
__global__ __launch_bounds__(1024) void k_fin(
    const float* __restrict__ P, int nP,
    const float* __restrict__ add, long ads,
    const float* __restrict__ gv, const float* __restrict__ bv,
    float* __restrict__ o) {
  int r = blockIdx.x, c = threadIdx.x;
  __shared__ float red[18];
  float v = add ? add[(size_t)r * ads + c] : 0.0f;
  for (int ks = 0; ks < nP; ks++) v += P[((size_t)ks * 16 + r) * HID + c];
  float m = block_sum(v, red, 16) * (1.0f / (float)HID);
  float d = v - m;
  float var = block_sum(d * d, red, 16) * (1.0f / (float)HID);
  float rs = 1.0f / sqrtf(var + 1e-3f);
  float y = d * rs * gv[c] + bv[c];
  float s = 1.0f / (1.0f + expf(-y));
  o[r * HID + c] = y * s;
}

// ---------------- init sample (mode) ----------------
__global__ __launch_bounds__(1024) void k_samp_init(
    const float* __restrict__ P, int nP, const float* __restrict__ bb,
    float* __restrict__ st) {
  int r = blockIdx.x, c = threadIdx.x;
  float acc = bb[c];
  for (int ks = 0; ks < nP; ks++) acc += P[((size_t)ks * 16 + r) * SD + c];
  int d = c & 31;
  float mx = acc;
#pragma unroll
  for (int m = 16; m >= 1; m >>= 1) mx = fmaxf(mx, __shfl_xor(mx, m, 32));
  float e = expf(acc - mx);
  float se = e;
#pragma unroll
  for (int m = 16; m >= 1; m >>= 1) se += __shfl_xor(se, m, 32);
  float p = 0.99f * (e / se) + 3.125e-4f;
  float by = p; int bi = d;
#pragma unroll
  for (int m = 16; m >= 1; m >>= 1) {
    float oy = __shfl_xor(by, m, 32);
    int oi = __shfl_xor(bi, m, 32);
    if (oy > by || (oy == by && oi < bi)) { by = oy; bi = oi; }
  }
  float oh = (d == bi) ? 1.0f : 0.0f;
  st[r * SD + c] = (oh + p) - p;
}

// ---------------- tiled GEMM: out[M x 1024] = A[M x K] @ Bw[K x 1024] (+bias) ----------
// 64x64 tiles, 4x4 micro, 256 thr, grid (16, M/64).
__global__ __launch_bounds__(256) void k_mm(const float* __restrict__ A, long lda,
                                            const float* __restrict__ Bw, int K,
                                            float* __restrict__ out, long ldo,
                                            const float* __restrict__ bias) {
  __shared__ float As[32][68];
  __shared__ float Bs[32][68];
  const int tid = threadIdx.x;
  const int tx = tid & 15, ty = tid >> 4;
  const int row0 = blockIdx.y * 64, col0 = blockIdx.x * 64;
  const int ar = tid >> 2, ak = (tid & 3) * 8;
  const int bk = tid >> 4, bc = (tid & 15) * 4;
  float acc[4][4] = {};
  const float* ap = A + (size_t)(row0 + ar) * lda + ak;
  const float* bp = Bw + (size_t)bk * HID + col0 + bc;
  for (int k0 = 0; k0 < K; k0 += 32) {
    float4 a0 = *(const float4*)(ap + k0);
    float4 a1 = *(const float4*)(ap + k0 + 4);
    float4 b0 = *(const float4*)(bp + (size_t)k0 * HID);
    float4 b1 = *(const float4*)(bp + (size_t)(k0 + 16) * HID);
    __syncthreads();
    As[ak + 0][ar] = a0.x; As[ak + 1][ar] = a0.y; As[ak + 2][ar] = a0.z; As[ak + 3][ar] = a0.w;
    As[ak + 4][ar] = a1.x; As[ak + 5][ar] = a1.y; As[ak + 6][ar] = a1.z; As[ak + 7][ar] = a1.w;
    *(float4*)&Bs[bk][bc] = b0;
    *(float4*)&Bs[bk + 16][bc] = b1;
    __syncthreads();
#pragma unroll
    for (int kk = 0; kk < 32; kk++) {
      float4 av = *(const float4*)&As[kk][ty * 4];
      float4 bv = *(const float4*)&Bs[kk][tx * 4];
      acc[0][0] += av.x * bv.x; acc[0][1] += av.x * bv.y; acc[0][2] += av.x * bv.z; acc[0][3] += av.x * bv.w;
      acc[1][0] += av.y * bv.x; acc[1][1] += av.y * bv.y; acc[1][2] += av.y * bv.z; acc[1][3] += av.y * bv.w;
      acc[2][0] += av.z * bv.x; acc[2][1] += av.z * bv.y; acc[2][2] += av.z * bv.z; acc[2][3] += av.z * bv.w;
      acc[3][0] += av.w * bv.x; acc[3][1] += av.w * bv.y; acc[3][2] += av.w * bv.z; acc[3][3] += av.w * bv.w;
    }
  }
#pragma unroll
  for (int i = 0; i < 4; i++) {
    float4 o;
    int col = col0 + tx * 4;
    o.x = acc[i][0] + (bias ? bias[col + 0] : 0.f);
    o.y = acc[i][1] + (bias ? bias[col + 1] : 0.f);
    o.z = acc[i][2] + (bias ? bias[col + 2] : 0.f);
    o.w = acc[i][3] + (bias ? bias[col + 3] : 0.f);
    *(float4*)(out + (size_t)(row0 + ty * 4 + i) * ldo + col) = o;
  }
}

// ---------------- deferred: per-row LN + silu in place ----------------
__global__ __launch_bounds__(256) void k_ln_rows(float* __restrict__ h,
                                                 const float* __restrict__ gv,
                                                 const float* __restrict__ bv) {
  int row = blockIdx.x, c0 = threadIdx.x * 4;
  __shared__ float red[18];
  float4 v = *(const float4*)(h + (size_t)row * HID + c0);
  float lsum = (v.x + v.y) + (v.z + v.w);
  float m = block_sum(lsum, red, 4) * (1.0f / (float)HID);
  float dx = v.x - m, dy = v.y - m, dz = v.z - m, dw = v.w - m;
  float lv = (dx * dx + dy * dy) + (dz * dz + dw * dw);
  float var = block_sum(lv, red, 4) * (1.0f / (float)HID);
  float rs = 1.0f / sqrtf(var + 1e-3f);
  float4 o;
  float y0 = dx * rs * gv[c0] + bv[c0];         o.x = y0 / (1.0f + expf(-y0));
  float y1 = dy * rs * gv[c0 + 1] + bv[c0 + 1]; o.y = y1 / (1.0f + expf(-y1));
  float y2 = dz * rs * gv[c0 + 2] + bv[c0 + 2]; o.z = y2 / (1.0f + expf(-y2));
  float y3 = dw * rs * gv[c0 + 3] + bv[c0 + 3]; o.w = y3 / (1.0f + expf(-y3));
  *(float4*)(h + (size_t)row * HID + c0) = o;
}

// ---------------- deferred: batched prior sample (logits in out+7168) ----------------
__global__ __launch_bounds__(1024) void k_samp_prior(float* __restrict__ out,
                                                     const float* __restrict__ gum) {
  int m = blockIdx.x, c = threadIdx.x;
  float lp = out[(size_t)m * OUT_C + 7168 + c];
  int d = c & 31;
  float mx = lp;
#pragma unroll
  for (int mm = 16; mm >= 1; mm >>= 1) mx = fmaxf(mx, __shfl_xor(mx, mm, 32));
  float e = expf(lp - mx);
  float se = e;
#pragma unroll
  for (int mm = 16; mm >= 1; mm >>= 1) se += __shfl_xor(se, mm, 32);
  float p = 0.99f * (e / se) + 3.125e-4f;
  float y = logf(p) + gum[(size_t)m * SD + c];
  float by = y; int bi = d;
#pragma unroll
  for (int mm = 16; mm >= 1; mm >>= 1) {
    float oy = __shfl_xor(by, mm, 32);
    int oi = __shfl_xor(bi, mm, 32);
    if (oy > by || (oy == by && oi < bi)) { by = oy; bi = oi; }
  }
  float oh = (d == bi) ? 1.0f : 0.0f;
  out[(size_t)m * OUT_C + 6144 + c] = (oh + p) - p;
}

// ---------------- GRU stage-1 reduce: sum splits + (sum, sumsq) per chunk ----------
__global__ __launch_bounds__(256) void k_red(const float* __restrict__ P, int nP,
                                             float* __restrict__ S,
                                             float* __restrict__ red_s, float* __restrict__ red_q) {
  int chunk = blockIdx.x, r = blockIdx.y;
  int c = chunk * 1024 + threadIdx.x * 4;
  float4 s = {0, 0, 0, 0};
  for (int ks = 0; ks < nP; ks++) {
    float4 v = *(const float4*)(P + ((size_t)ks * 16 + r) * (3 * DET) + c);
    s.x += v.x; s.y += v.y; s.z += v.z; s.w += v.w;
  }
  *(float4*)(S + (size_t)r * (3 * DET) + c) = s;
  float sx = (s.x + s.y) + (s.z + s.w);
  float sq = (s.x * s.x + s.y * s.y) + (s.z * s.z + s.w * s.w);
  __shared__ float rbuf[8];
#pragma unroll
  for (int m = 32; m >= 1; m >>= 1) { sx += __shfl_xor(sx, m, 64); sq += __shfl_xor(sq, m, 64); }
  int wid = threadIdx.x >> 6;
  if ((threadIdx.x & 63) == 0) { rbuf[wid] = sx; rbuf[4 + wid] = sq; }
  __syncthreads();
  if (threadIdx.x == 0) {
    red_s[r * 12 + chunk] = (rbuf[0] + rbuf[1]) + (rbuf[2] + rbuf[3]);
    red_q[r * 12 + chunk] = (rbuf[4] + rbuf[5]) + (rbuf[6] + rbuf[7]);
  }
}

// ---------------- GRU stage-2: LN + gates + deter_new + next-step deter blend ----------
__global__ __launch_bounds__(1024) void k_gru_gate(
    const float* __restrict__ S, const float* __restrict__ red_s, const float* __restrict__ red_q,
    const float* __restrict__ g, const float* __restrict__ b,
    float* __restrict__ deter_in, float* __restrict__ deter_new,
    float* __restrict__ out_deter, const float* __restrict__ isf, int t,
    const float* __restrict__ init_deter) {
  int r = blockIdx.x;
  __shared__ float mv[2];
  if (threadIdx.x == 0) {
    float s = 0.f, q = 0.f;
    for (int k2 = 0; k2 < 12; k2++) { s += red_s[r * 12 + k2]; q += red_q[r * 12 + k2]; }
    float m = s * (1.0f / (float)(3 * DET));
    float var = q * (1.0f / (float)(3 * DET)) - m * m;
    mv[0] = m; mv[1] = 1.0f / sqrtf(var + 1e-3f);
  }
  __syncthreads();
  float m = mv[0], rs = mv[1];
  float ft = (t + 1 < T_STEPS) ? isf[r * T_STEPS + t + 1] : 0.0f;
  for (int j = threadIdx.x; j < DET; j += 1024) {
    float lr = (S[(size_t)r * (3 * DET) + j] - m) * rs * g[j] + b[j];
    float lc = (S[(size_t)r * (3 * DET) + j + DET] - m) * rs * g[j + DET] + b[j + DET];
    float lu = (S[(size_t)r * (3 * DET) + j + 2 * DET] - m) * rs * g[j + 2 * DET] + b[j + 2 * DET];
    float rr = 1.0f / (1.0f + expf(-lr));
    float cd = tanhf(rr * lc);
    float uu = 1.0f / (1.0f + expf(-(lu - 1.0f)));
    float dn = uu * cd + (1.0f - uu) * deter_in[r * DET + j];
    deter_new[r * DET + j] = dn;
    out_deter[(size_t)r * OUT_RSTRIDE + j] = dn;
    deter_in[r * DET + j] = dn * (1.0f - ft) + init_deter[j] * ft;
  }
}

// ---------------- post sample + next-step stoch/a blend ----------------
__global__ __launch_bounds__(1024) void k_samp(
    const float* __restrict__ P, int nP, const float* __restrict__ bb,
    const float* __restrict__ gum, long gs,
    float* __restrict__ st, long ss, float* __restrict__ lg, long ls,
    const float* __restrict__ isf, const float* __restrict__ pa, int t,
    float* __restrict__ stoch_in, float* __restrict__ a_eff,
    const float* __restrict__ init_stoch) {
  int r = blockIdx.x, c = threadIdx.x;
  float acc = bb[c];
  for (int ks = 0; ks < nP; ks++) acc += P[((size_t)ks * 16 + r) * SD + c];
  int d = c & 31;
  float mx = acc;
#pragma unroll
  for (int m = 16; m >= 1; m >>= 1) mx = fmaxf(mx, __shfl_xor(mx, m, 32));
  float e = expf(acc - mx);
  float se = e;
#pragma unroll
  for (int m = 16; m >= 1; m >>= 1) se += __shfl_xor(se, m, 32);
  float p = 0.99f * (e / se) + 3.125e-4f;
  float y = logf(p) + gum[(long)r * gs + c];
  float by = y; int bi = d;
#pragma unroll
  for (int m = 16; m >= 1; m >>= 1) {
    float oy = __shfl_xor(by, m, 32);
    int oi = __shfl_xor(bi, m, 32);
    if (oy > by || (oy == by && oi < bi)) { by = oy; bi = oi; }
  }
  float oh = (d == bi) ? 1.0f : 0.0f;
  float outv = (oh + p) - p;
  st[(long)r * ss + c] = outv;
  lg[(long)r * ls + c] = acc;
  float fn = (t + 1 < T_STEPS) ? isf[r * T_STEPS + t + 1] : 0.0f;
  stoch_in[r * SD + c] = outv * (1.0f - fn) + init_stoch[r * SD + c] * fn;
  if (c < A_DIM) {
    float a = (t + 1 < T_STEPS) ? pa[(r * T_STEPS + t + 1) * A_DIM + c] : 0.0f;
    a = a * (1.0f / fmaxf(fabsf(a), 1.0f));
    a_eff[r * 8 + c] = a * (1.0f - fn);
  }
}

// ---------------- host ----------------
static inline GemmArgs mkargs(const float* A0, long sA0, int cA0,
                              const float* A1, long sA1,
                              const float* W, int N, int Ktot, int KS, int nsplit, float* P) {
  GemmArgs g; g.A0 = A0; g.sA0 = sA0; g.cA0 = cA0; g.A1 = A1; g.sA1 = sA1;
  g.W = W; g.N = N; g.Ktot = Ktot; g.KS = KS; g.nsplit = nsplit; g.P = P;
  return g;
}

extern "C" void kernel_launch(void* const* d_in, const int* in_sizes, int n_in,
                              void* d_out, int out_size, void* d_ws, size_t ws_size,
                              hipStream_t stream) {
  const float* embed  = (const float*)d_in[0];
  const float* pa     = (const float*)d_in[1];
  const float* isf    = (const float*)d_in[2];
  const float* gprior = (const float*)d_in[3];
  const float* gpost  = (const float*)d_in[4];
  const float* w_init = (const float*)d_in[5];
  const float* W1  = (const float*)d_in[6];
  const float* g1  = (const float*)d_in[7];
  const float* b1  = (const float*)d_in[8];
  const float* Wg  = (const float*)d_in[9];
  const float* gg  = (const float*)d_in[10];
  const float* bg  = (const float*)d_in[11];
  const float* W2a = (const float*)d_in[12];
  const float* g2  = (const float*)d_in[13];
  const float* b2  = (const float*)d_in[14];
  const float* W2b = (const float*)d_in[15];
  const float* bb2 = (const float*)d_in[16];
  const float* Wo  = (const float*)d_in[17];
  const float* go  = (const float*)d_in[18];
  const float* bo  = (const float*)d_in[19];
  const float* Wob = (const float*)d_in[20];
  const float* bbo = (const float*)d_in[21];
  float* out = (float*)d_out;
  float* ws  = (float*)d_ws;

  // workspace (floats)
  float* Pg    = ws;                    // 20*16*12288 = 3,932,160 (aliased: h_all deferred)
  float* h_all = Pg;                    // 1024*1024
  float* Sg    = Pg + 3932160;          // 196,608
  float* red_s = Sg + 196608;           // 192
  float* red_q = red_s + 192;           // 192 (+pad)
  float* Pimg1 = red_s + 512;           // 17*16*1024 = 278,528
  float* Pb    = Pimg1 + 278528;        // 32*16*1024 = 524,288
  float* Ps1   = Pb + 524288;           // 16*16*1024 = 262,144
  float* st_   = Ps1 + 262144;
  float* init_stoch = st_;              // 16,384
  float* init_deter = st_ + 16384;      // 4,096
  float* stoch_in   = st_ + 20480;      // 16,384
  float* deter_in   = st_ + 36864;      // 65,536
  float* deter_new  = st_ + 102400;     // 65,536
  float* a_eff      = st_ + 167936;     // 128
  float* x          = st_ + 168064;     // 16,384
  float* h2         = st_ + 184448;     // 16,384

  // ---- OE precompute: e @ Wo[0:E] -> out post-logit slots (consumed in-loop, overwritten)
  k_mm<<<dim3(16, 16), 256, 0, stream>>>(embed, E_DIM, Wo, E_DIM, out + 5120, OUT_C, nullptr);

  // ---- init: init_deter = tanh(w_init); init_stoch = st_mode(prior_logits(init_deter))
  k_tanh<<<4, 1024, 0, stream>>>(w_init, init_deter);
  k_gemm<true><<<dim3(2, 32), 256, 0, stream>>>(
      mkargs(init_deter, 0, DET, nullptr, 0, W2a, HID, DET, 128, 32, Pb));
  k_fin<<<16, 1024, 0, stream>>>(Pb, 32, nullptr, 0, g2, b2, x);
  k_gemm<true><<<dim3(2, 16), 256, 0, stream>>>(
      mkargs(x, HID, HID, nullptr, 0, W2b, SD, HID, 64, 16, Ps1));
  k_samp_init<<<16, 1024, 0, stream>>>(Ps1, 16, bb2, init_stoch);

  // ---- t=0 prep (f[:,0]==1 -> all init) ----
  k_prep<<<16, 256, 0, stream>>>(isf, pa, 0, init_stoch, init_deter, 0,
                                 init_stoch, init_deter, stoch_in, deter_in, a_eff);

  for (int t = 0; t < T_STEPS; t++) {
    // img1: concat(stoch,a)[1030] @ W1 -> 1024
    k_gemm<true><<<dim3(2, 17), 256, 0, stream>>>(
        mkargs(stoch_in, SD, SD, a_eff, 8, W1, HID, SD + A_DIM, 64, 17, Pimg1));
    k_fin<<<16, 1024, 0, stream>>>(Pimg1, 17, nullptr, 0, g1, b1, x);
    // GRU: concat(x,deter_in)[5120] @ Wg -> 12288 (Wg cacheable for L3 residency)
    k_gemm<false><<<dim3(24, 20), 256, 0, stream>>>(
        mkargs(x, HID, HID, deter_in, DET, Wg, 3 * DET, HID + DET, 256, 20, Pg));
    k_red<<<dim3(12, 16), 256, 0, stream>>>(Pg, 20, Sg, red_s, red_q);
    k_gru_gate<<<16, 1024, 0, stream>>>(Sg, red_s, red_q, gg, bg, deter_in, deter_new,
                                        out + (size_t)t * OUT_C + 1024, isf, t, init_deter);
    // obs deter-part: deter_new[4096] @ Wo[E:] -> 1024
    k_gemm<true><<<dim3(2, 32), 256, 0, stream>>>(
        mkargs(deter_new, DET, DET, nullptr, 0, Wo + (size_t)E_DIM * HID, HID, DET, 128, 32, Pb));
    k_fin<<<16, 1024, 0, stream>>>(Pb, 32, out + (size_t)t * OUT_C + 5120, OUT_RSTRIDE,
                                   go, bo, h2);
    // post-sample GEMM: h2 @ Wob
    k_gemm<true><<<dim3(2, 16), 256, 0, stream>>>(
        mkargs(h2, HID, HID, nullptr, 0, Wob, SD, HID, 64, 16, Ps1));
    k_samp<<<16, 1024, 0, stream>>>(
        Ps1, 16, bbo, gpost + (size_t)t * SD, (long)T_STEPS * SD,
        out + (size_t)t * OUT_C + 0, OUT_RSTRIDE,
        out + (size_t)t * OUT_C + 5120, OUT_RSTRIDE,
        isf, pa, t, stoch_in, a_eff, init_stoch);
  }

  // ---- deferred prior branch (batched over all (b,t)) ----
  k_mm<<<dim3(16, 16), 256, 0, stream>>>(out + 1024, OUT_C, W2a, DET, h_all, HID, nullptr);
  k_ln_rows<<<1024, 256, 0, stream>>>(h_all, g2, b2);
  k_mm<<<dim3(16, 16), 256, 0, stream>>>(h_all, HID, W2b, HID, out + 7168, OUT_C, bb2);
  k_samp_prior<<<1024, 1024, 0, stream>>>(out, gprior);
}

// Round 6
// 11296.125 us; speedup vs baseline: 4.9320x; 1.6674x over previous
//
#include <hip/hip_runtime.h>
#include <cmath>

// RSSM scan: B=16, T=64, A=6, E=12288, DET=4096, HID=1024, S=32, D=32
// fp32 throughout (argmax stability). Deterministic fixed-order reductions.
// Multi-kernel (no cooperative launch: grid.sync measured ~150us/sync on MI355X).
// This round: round-3 GEMM body (unroll 4) + deferred prior branch.

#define B 16
#define T_STEPS 64
#define A_DIM 6
#define E_DIM 12288
#define DET 4096
#define HID 1024
#define SD 1024
#define OUT_C 8192
#define OUT_RSTRIDE (T_STEPS * OUT_C)

typedef float f2v __attribute__((ext_vector_type(2)));

// ---------------- block reduce (deterministic) ----------------
__device__ __forceinline__ float block_sum(float v, float* red, int nw) {
#pragma unroll
  for (int m = 32; m >= 1; m >>= 1) v += __shfl_xor(v, m, 64);
  int wid = threadIdx.x >> 6;
  if ((threadIdx.x & 63) == 0) red[wid] = v;
  __syncthreads();
  if (wid == 0) {
    float s = ((int)threadIdx.x < nw) ? red[threadIdx.x] : 0.0f;
#pragma unroll
    for (int m = 8; m >= 1; m >>= 1) s += __shfl_xor(s, m, 16);
    if (threadIdx.x == 0) red[0] = s;
  }
  __syncthreads();
  float out = red[0];
  __syncthreads();
  return out;
}

__global__ __launch_bounds__(1024) void k_tanh(const float* __restrict__ w, float* __restrict__ o) {
  int i = blockIdx.x * 1024 + threadIdx.x;
  if (i < DET) o[i] = tanhf(w[i]);
}

// ---------------- prep (t=0 only) ----------------
__global__ __launch_bounds__(256) void k_prep(
    const float* __restrict__ isf, const float* __restrict__ pa, int t,
    const float* __restrict__ stoch_prev,
    const float* __restrict__ deter_prev, long deter_prev_stride,
    const float* __restrict__ init_stoch, const float* __restrict__ init_deter_row,
    float* __restrict__ stoch_in, float* __restrict__ deter_in, float* __restrict__ a_eff) {
  int r = blockIdx.x;
  float f = isf[r * T_STEPS + t];
  float omf = 1.0f - f;
  for (int c = threadIdx.x; c < SD; c += 256)
    stoch_in[r * SD + c] = stoch_prev[r * SD + c] * omf + init_stoch[r * SD + c] * f;
  for (int c = threadIdx.x; c < DET; c += 256)
    deter_in[r * DET + c] = deter_prev[(long)r * deter_prev_stride + c] * omf + init_deter_row[c] * f;
  if ((int)threadIdx.x < A_DIM) {
    float a = pa[(r * T_STEPS + t) * A_DIM + threadIdx.x];
    a = a * (1.0f / fmaxf(fabsf(a), 1.0f));
    a_eff[r * 8 + threadIdx.x] = a * omf;
  }
}

// ---------------- K-split GEMM: P[split][16][N] partials (round-3 body) ----------------
struct GemmArgs {
  const float* A0; long sA0; int cA0;
  const float* A1; long sA1;
  const float* W; int N; int Ktot; int KS; int nsplit;
  float* P;
};

template <bool NT>
__global__ __launch_bounds__(256) void k_gemm(GemmArgs g) {
  if ((int)blockIdx.y >= g.nsplit) return;
  const int tid = threadIdx.x;
  const int c0 = blockIdx.x * 512 + tid * 2;
  const int k0 = (int)blockIdx.y * g.KS;
  __shared__ float in_s[16][64];
  float acc[16][2];
#pragma unroll
  for (int r = 0; r < 16; r++) { acc[r][0] = 0.f; acc[r][1] = 0.f; }
  for (int kb = 0; kb < g.KS; kb += 64) {
    const int kbase = k0 + kb;
#pragma unroll
    for (int j = 0; j < 4; j++) {
      int ii = tid + j * 256;
      int r = ii >> 6, kk = ii & 63;
      int k = kbase + kk;
      float v = 0.f;
      if (k < g.cA0) v = g.A0[(long)r * g.sA0 + k];
      else if (k < g.Ktot) v = g.A1[(long)r * g.sA1 + (k - g.cA0)];
      in_s[r][kk] = v;
    }
    __syncthreads();
    if (kbase + 64 <= g.Ktot) {
      const float* wp = g.W + (size_t)kbase * g.N + c0;
#pragma unroll 4
      for (int kk = 0; kk < 64; kk++) {
        f2v w = NT ? __builtin_nontemporal_load((const f2v*)wp) : *(const f2v*)wp;
        wp += g.N;
#pragma unroll
        for (int r = 0; r < 16; r++) {
          acc[r][0] += in_s[r][kk] * w[0]; acc[r][1] += in_s[r][kk] * w[1];
        }
      }
    } else {  // K tail (img1: Ktot=1030)
#pragma unroll 4
      for (int kk = 0; kk < 64; kk++) {
        int krow = kbase + kk; if (krow >= g.Ktot) krow = g.Ktot - 1;
        const f2v w = *(const f2v*)(g.W + (size_t)krow * g.N + c0);
#pragma unroll
        for (int r = 0; r < 16; r++) {
          acc[r][0] += in_s[r][kk] * w[0]; acc[r][1] += in_s[r][kk] * w[1];
        }
      }
    }
    __syncthreads();
  }
#pragma unroll
  for (int r = 0; r < 16; r++)
    *(f2v*)(g.P + ((size_t)blockIdx.y * 16 + r) * g.N + c0) = f2v{acc[r][0], acc[r][1]};
}

// ---------------- finish: (optional add) + sum partials + LN + silu ----------------
__global__ __launch_bounds__(1024) void k_fin(
    const float* __restrict__ P, int nP,
    const float* __restrict__ add, long ads,
    const float* __restrict__ gv, const float* __restrict__ bv,
    float* __restrict__ o) {
  int r = blockIdx.x, c = threadIdx.x;
  __shared__ float red[18];
  float v = add ? add[(size_t)r * ads + c] : 0.0f;
  for (int ks = 0; ks < nP; ks++) v += P[((size_t)ks * 16 + r) * HID + c];
  float m = block_sum(v, red, 16) * (1.0f / (float)HID);
  float d = v - m;
  float var = block_sum(d * d, red, 16) * (1.0f / (float)HID);
  float rs = 1.0f / sqrtf(var + 1e-3f);
  float y = d * rs * gv[c] + bv[c];
  float s = 1.0f / (1.0f + expf(-y));
  o[r * HID + c] = y * s;
}

// ---------------- init sample (mode) ----------------
__global__ __launch_bounds__(1024) void k_samp_init(
    const float* __restrict__ P, int nP, const float* __restrict__ bb,
    float* __restrict__ st) {
  int r = blockIdx.x, c = threadIdx.x;
  float acc = bb[c];
  for (int ks = 0; ks < nP; ks++) acc += P[((size_t)ks * 16 + r) * SD + c];
  int d = c & 31;
  float mx = acc;
#pragma unroll
  for (int m = 16; m >= 1; m >>= 1) mx = fmaxf(mx, __shfl_xor(mx, m, 32));
  float e = expf(acc - mx);
  float se = e;
#pragma unroll
  for (int m = 16; m >= 1; m >>= 1) se += __shfl_xor(se, m, 32);
  float p = 0.99f * (e / se) + 3.125e-4f;
  float by = p; int bi = d;
#pragma unroll
  for (int m = 16; m >= 1; m >>= 1) {
    float oy = __shfl_xor(by, m, 32);
    int oi = __shfl_xor(bi, m, 32);
    if (oy > by || (oy == by && oi < bi)) { by = oy; bi = oi; }
  }
  float oh = (d == bi) ? 1.0f : 0.0f;
  st[r * SD + c] = (oh + p) - p;
}

// ---------------- tiled GEMM: out[M x 1024] = A[M x K] @ Bw[K x 1024] (+bias) ----------
__global__ __launch_bounds__(256) void k_mm(const float* __restrict__ A, long lda,
                                            const float* __restrict__ Bw, int K,
                                            float* __restrict__ out, long ldo,
                                            const float* __restrict__ bias) {
  __shared__ float As[32][68];
  __shared__ float Bs[32][68];
  const int tid = threadIdx.x;
  const int tx = tid & 15, ty = tid >> 4;
  const int row0 = blockIdx.y * 64, col0 = blockIdx.x * 64;
  const int ar = tid >> 2, ak = (tid & 3) * 8;
  const int bk = tid >> 4, bc = (tid & 15) * 4;
  float acc[4][4] = {};
  const float* ap = A + (size_t)(row0 + ar) * lda + ak;
  const float* bp = Bw + (size_t)bk * HID + col0 + bc;
  for (int k0 = 0; k0 < K; k0 += 32) {
    float4 a0 = *(const float4*)(ap + k0);
    float4 a1 = *(const float4*)(ap + k0 + 4);
    float4 b0 = *(const float4*)(bp + (size_t)k0 * HID);
    float4 b1 = *(const float4*)(bp + (size_t)(k0 + 16) * HID);
    __syncthreads();
    As[ak + 0][ar] = a0.x; As[ak + 1][ar] = a0.y; As[ak + 2][ar] = a0.z; As[ak + 3][ar] = a0.w;
    As[ak + 4][ar] = a1.x; As[ak + 5][ar] = a1.y; As[ak + 6][ar] = a1.z; As[ak + 7][ar] = a1.w;
    *(float4*)&Bs[bk][bc] = b0;
    *(float4*)&Bs[bk + 16][bc] = b1;
    __syncthreads();
#pragma unroll
    for (int kk = 0; kk < 32; kk++) {
      float4 av = *(const float4*)&As[kk][ty * 4];
      float4 bv = *(const float4*)&Bs[kk][tx * 4];
      acc[0][0] += av.x * bv.x; acc[0][1] += av.x * bv.y; acc[0][2] += av.x * bv.z; acc[0][3] += av.x * bv.w;
      acc[1][0] += av.y * bv.x; acc[1][1] += av.y * bv.y; acc[1][2] += av.y * bv.z; acc[1][3] += av.y * bv.w;
      acc[2][0] += av.z * bv.x; acc[2][1] += av.z * bv.y; acc[2][2] += av.z * bv.z; acc[2][3] += av.z * bv.w;
      acc[3][0] += av.w * bv.x; acc[3][1] += av.w * bv.y; acc[3][2] += av.w * bv.z; acc[3][3] += av.w * bv.w;
    }
  }
#pragma unroll
  for (int i = 0; i < 4; i++) {
    float4 o;
    int col = col0 + tx * 4;
    o.x = acc[i][0] + (bias ? bias[col + 0] : 0.f);
    o.y = acc[i][1] + (bias ? bias[col + 1] : 0.f);
    o.z = acc[i][2] + (bias ? bias[col + 2] : 0.f);
    o.w = acc[i][3] + (bias ? bias[col + 3] : 0.f);
    *(float4*)(out + (size_t)(row0 + ty * 4 + i) * ldo + col) = o;
  }
}

// ---------------- deferred: per-row LN + silu in place ----------------
__global__ __launch_bounds__(256) void k_ln_rows(float* __restrict__ h,
                                                 const float* __restrict__ gv,
                                                 const float* __restrict__ bv) {
  int row = blockIdx.x, c0 = threadIdx.x * 4;
  __shared__ float red[18];
  float4 v = *(const float4*)(h + (size_t)row * HID + c0);
  float lsum = (v.x + v.y) + (v.z + v.w);
  float m = block_sum(lsum, red, 4) * (1.0f / (float)HID);
  float dx = v.x - m, dy = v.y - m, dz = v.z - m, dw = v.w - m;
  float lv = (dx * dx + dy * dy) + (dz * dz + dw * dw);
  float var = block_sum(lv, red, 4) * (1.0f / (float)HID);
  float rs = 1.0f / sqrtf(var + 1e-3f);
  float4 o;
  float y0 = dx * rs * gv[c0] + bv[c0];         o.x = y0 / (1.0f + expf(-y0));
  float y1 = dy * rs * gv[c0 + 1] + bv[c0 + 1]; o.y = y1 / (1.0f + expf(-y1));
  float y2 = dz * rs * gv[c0 + 2] + bv[c0 + 2]; o.z = y2 / (1.0f + expf(-y2));
  float y3 = dw * rs * gv[c0 + 3] + bv[c0 + 3]; o.w = y3 / (1.0f + expf(-y3));
  *(float4*)(h + (size_t)row * HID + c0) = o;
}

// ---------------- deferred: batched prior sample (logits in out+7168) ----------------
__global__ __launch_bounds__(1024) void k_samp_prior(float* __restrict__ out,
                                                     const float* __restrict__ gum) {
  int m = blockIdx.x, c = threadIdx.x;
  float lp = out[(size_t)m * OUT_C + 7168 + c];
  int d = c & 31;
  float mx = lp;
#pragma unroll
  for (int mm = 16; mm >= 1; mm >>= 1) mx = fmaxf(mx, __shfl_xor(mx, mm, 32));
  float e = expf(lp - mx);
  float se = e;
#pragma unroll
  for (int mm = 16; mm >= 1; mm >>= 1) se += __shfl_xor(se, mm, 32);
  float p = 0.99f * (e / se) + 3.125e-4f;
  float y = logf(p) + gum[(size_t)m * SD + c];
  float by = y; int bi = d;
#pragma unroll
  for (int mm = 16; mm >= 1; mm >>= 1) {
    float oy = __shfl_xor(by, mm, 32);
    int oi = __shfl_xor(bi, mm, 32);
    if (oy > by || (oy == by && oi < bi)) { by = oy; bi = oi; }
  }
  float oh = (d == bi) ? 1.0f : 0.0f;
  out[(size_t)m * OUT_C + 6144 + c] = (oh + p) - p;
}

// ---------------- GRU stage-1 reduce: sum splits + (sum, sumsq) per chunk ----------
__global__ __launch_bounds__(256) void k_red(const float* __restrict__ P, int nP,
                                             float* __restrict__ S,
                                             float* __restrict__ red_s, float* __restrict__ red_q) {
  int chunk = blockIdx.x, r = blockIdx.y;
  int c = chunk * 1024 + threadIdx.x * 4;
  float4 s = {0, 0, 0, 0};
  for (int ks = 0; ks < nP; ks++) {
    float4 v = *(const float4*)(P + ((size_t)ks * 16 + r) * (3 * DET) + c);
    s.x += v.x; s.y += v.y; s.z += v.z; s.w += v.w;
  }
  *(float4*)(S + (size_t)r * (3 * DET) + c) = s;
  float sx = (s.x + s.y) + (s.z + s.w);
  float sq = (s.x * s.x + s.y * s.y) + (s.z * s.z + s.w * s.w);
  __shared__ float rbuf[8];
#pragma unroll
  for (int m = 32; m >= 1; m >>= 1) { sx += __shfl_xor(sx, m, 64); sq += __shfl_xor(sq, m, 64); }
  int wid = threadIdx.x >> 6;
  if ((threadIdx.x & 63) == 0) { rbuf[wid] = sx; rbuf[4 + wid] = sq; }
  __syncthreads();
  if (threadIdx.x == 0) {
    red_s[r * 12 + chunk] = (rbuf[0] + rbuf[1]) + (rbuf[2] + rbuf[3]);
    red_q[r * 12 + chunk] = (rbuf[4] + rbuf[5]) + (rbuf[6] + rbuf[7]);
  }
}

// ---------------- GRU stage-2: LN + gates + deter_new + next-step deter blend ----------
__global__ __launch_bounds__(1024) void k_gru_gate(
    const float* __restrict__ S, const float* __restrict__ red_s, const float* __restrict__ red_q,
    const float* __restrict__ g, const float* __restrict__ b,
    float* __restrict__ deter_in, float* __restrict__ deter_new,
    float* __restrict__ out_deter, const float* __restrict__ isf, int t,
    const float* __restrict__ init_deter) {
  int r = blockIdx.x;
  __shared__ float mv[2];
  if (threadIdx.x == 0) {
    float s = 0.f, q = 0.f;
    for (int k2 = 0; k2 < 12; k2++) { s += red_s[r * 12 + k2]; q += red_q[r * 12 + k2]; }
    float m = s * (1.0f / (float)(3 * DET));
    float var = q * (1.0f / (float)(3 * DET)) - m * m;
    mv[0] = m; mv[1] = 1.0f / sqrtf(var + 1e-3f);
  }
  __syncthreads();
  float m = mv[0], rs = mv[1];
  float ft = (t + 1 < T_STEPS) ? isf[r * T_STEPS + t + 1] : 0.0f;
  for (int j = threadIdx.x; j < DET; j += 1024) {
    float lr = (S[(size_t)r * (3 * DET) + j] - m) * rs * g[j] + b[j];
    float lc = (S[(size_t)r * (3 * DET) + j + DET] - m) * rs * g[j + DET] + b[j + DET];
    float lu = (S[(size_t)r * (3 * DET) + j + 2 * DET] - m) * rs * g[j + 2 * DET] + b[j + 2 * DET];
    float rr = 1.0f / (1.0f + expf(-lr));
    float cd = tanhf(rr * lc);
    float uu = 1.0f / (1.0f + expf(-(lu - 1.0f)));
    float dn = uu * cd + (1.0f - uu) * deter_in[r * DET + j];
    deter_new[r * DET + j] = dn;
    out_deter[(size_t)r * OUT_RSTRIDE + j] = dn;
    deter_in[r * DET + j] = dn * (1.0f - ft) + init_deter[j] * ft;
  }
}

// ---------------- post sample + next-step stoch/a blend ----------------
__global__ __launch_bounds__(1024) void k_samp(
    const float* __restrict__ P, int nP, const float* __restrict__ bb,
    const float* __restrict__ gum, long gs,
    float* __restrict__ st, long ss, float* __restrict__ lg, long ls,
    const float* __restrict__ isf, const float* __restrict__ pa, int t,
    float* __restrict__ stoch_in, float* __restrict__ a_eff,
    const float* __restrict__ init_stoch) {
  int r = blockIdx.x, c = threadIdx.x;
  float acc = bb[c];
  for (int ks = 0; ks < nP; ks++) acc += P[((size_t)ks * 16 + r) * SD + c];
  int d = c & 31;
  float mx = acc;
#pragma unroll
  for (int m = 16; m >= 1; m >>= 1) mx = fmaxf(mx, __shfl_xor(mx, m, 32));
  float e = expf(acc - mx);
  float se = e;
#pragma unroll
  for (int m = 16; m >= 1; m >>= 1) se += __shfl_xor(se, m, 32);
  float p = 0.99f * (e / se) + 3.125e-4f;
  float y = logf(p) + gum[(long)r * gs + c];
  float by = y; int bi = d;
#pragma unroll
  for (int m = 16; m >= 1; m >>= 1) {
    float oy = __shfl_xor(by, m, 32);
    int oi = __shfl_xor(bi, m, 32);
    if (oy > by || (oy == by && oi < bi)) { by = oy; bi = oi; }
  }
  float oh = (d == bi) ? 1.0f : 0.0f;
  float outv = (oh + p) - p;
  st[(long)r * ss + c] = outv;
  lg[(long)r * ls + c] = acc;
  float fn = (t + 1 < T_STEPS) ? isf[r * T_STEPS + t + 1] : 0.0f;
  stoch_in[r * SD + c] = outv * (1.0f - fn) + init_stoch[r * SD + c] * fn;
  if (c < A_DIM) {
    float a = (t + 1 < T_STEPS) ? pa[(r * T_STEPS + t + 1) * A_DIM + c] : 0.0f;
    a = a * (1.0f / fmaxf(fabsf(a), 1.0f));
    a_eff[r * 8 + c] = a * (1.0f - fn);
  }
}

// ---------------- host ----------------
static inline GemmArgs mkargs(const float* A0, long sA0, int cA0,
                              const float* A1, long sA1,
                              const float* W, int N, int Ktot, int KS, int nsplit, float* P) {
  GemmArgs g; g.A0 = A0; g.sA0 = sA0; g.cA0 = cA0; g.A1 = A1; g.sA1 = sA1;
  g.W = W; g.N = N; g.Ktot = Ktot; g.KS = KS; g.nsplit = nsplit; g.P = P;
  return g;
}

extern "C" void kernel_launch(void* const* d_in, const int* in_sizes, int n_in,
                              void* d_out, int out_size, void* d_ws, size_t ws_size,
                              hipStream_t stream) {
  const float* embed  = (const float*)d_in[0];
  const float* pa     = (const float*)d_in[1];
  const float* isf    = (const float*)d_in[2];
  const float* gprior = (const float*)d_in[3];
  const float* gpost  = (const float*)d_in[4];
  const float* w_init = (const float*)d_in[5];
  const float* W1  = (const float*)d_in[6];
  const float* g1  = (const float*)d_in[7];
  const float* b1  = (const float*)d_in[8];
  const float* Wg  = (const float*)d_in[9];
  const float* gg  = (const float*)d_in[10];
  const float* bg  = (const float*)d_in[11];
  const float* W2a = (const float*)d_in[12];
  const float* g2  = (const float*)d_in[13];
  const float* b2  = (const float*)d_in[14];
  const float* W2b = (const float*)d_in[15];
  const float* bb2 = (const float*)d_in[16];
  const float* Wo  = (const float*)d_in[17];
  const float* go  = (const float*)d_in[18];
  const float* bo  = (const float*)d_in[19];
  const float* Wob = (const float*)d_in[20];
  const float* bbo = (const float*)d_in[21];
  float* out = (float*)d_out;
  float* ws  = (float*)d_ws;

  // workspace (floats)
  float* Pg    = ws;                    // 20*16*12288 = 3,932,160 (aliased: h_all deferred)
  float* h_all = Pg;                    // 1024*1024
  float* Sg    = Pg + 3932160;          // 196,608
  float* red_s = Sg + 196608;           // 192
  float* red_q = red_s + 192;           // 192 (+pad)
  float* Pimg1 = red_s + 512;           // 17*16*1024 = 278,528
  float* Pb    = Pimg1 + 278528;        // 32*16*1024 = 524,288
  float* Ps1   = Pb + 524288;           // 16*16*1024 = 262,144
  float* st_   = Ps1 + 262144;
  float* init_stoch = st_;              // 16,384
  float* init_deter = st_ + 16384;      // 4,096
  float* stoch_in   = st_ + 20480;      // 16,384
  float* deter_in   = st_ + 36864;      // 65,536
  float* deter_new  = st_ + 102400;     // 65,536
  float* a_eff      = st_ + 167936;     // 128
  float* x          = st_ + 168064;     // 16,384
  float* h2         = st_ + 184448;     // 16,384

  // ---- OE precompute: e @ Wo[0:E] -> out post-logit slots (consumed in-loop, overwritten)
  k_mm<<<dim3(16, 16), 256, 0, stream>>>(embed, E_DIM, Wo, E_DIM, out + 5120, OUT_C, nullptr);

  // ---- init: init_deter = tanh(w_init); init_stoch = st_mode(prior_logits(init_deter))
  k_tanh<<<4, 1024, 0, stream>>>(w_init, init_deter);
  k_gemm<true><<<dim3(2, 32), 256, 0, stream>>>(
      mkargs(init_deter, 0, DET, nullptr, 0, W2a, HID, DET, 128, 32, Pb));
  k_fin<<<16, 1024, 0, stream>>>(Pb, 32, nullptr, 0, g2, b2, x);
  k_gemm<true><<<dim3(2, 16), 256, 0, stream>>>(
      mkargs(x, HID, HID, nullptr, 0, W2b, SD, HID, 64, 16, Ps1));
  k_samp_init<<<16, 1024, 0, stream>>>(Ps1, 16, bb2, init_stoch);

  // ---- t=0 prep (f[:,0]==1 -> all init) ----
  k_prep<<<16, 256, 0, stream>>>(isf, pa, 0, init_stoch, init_deter, 0,
                                 init_stoch, init_deter, stoch_in, deter_in, a_eff);

  for (int t = 0; t < T_STEPS; t++) {
    // img1: concat(stoch,a)[1030] @ W1 -> 1024
    k_gemm<true><<<dim3(2, 17), 256, 0, stream>>>(
        mkargs(stoch_in, SD, SD, a_eff, 8, W1, HID, SD + A_DIM, 64, 17, Pimg1));
    k_fin<<<16, 1024, 0, stream>>>(Pimg1, 17, nullptr, 0, g1, b1, x);
    // GRU: concat(x,deter_in)[5120] @ Wg -> 12288 (Wg cacheable for L3 residency)
    k_gemm<false><<<dim3(24, 20), 256, 0, stream>>>(
        mkargs(x, HID, HID, deter_in, DET, Wg, 3 * DET, HID + DET, 256, 20, Pg));
    k_red<<<dim3(12, 16), 256, 0, stream>>>(Pg, 20, Sg, red_s, red_q);
    k_gru_gate<<<16, 1024, 0, stream>>>(Sg, red_s, red_q, gg, bg, deter_in, deter_new,
                                        out + (size_t)t * OUT_C + 1024, isf, t, init_deter);
    // obs deter-part: deter_new[4096] @ Wo[E:] -> 1024
    k_gemm<true><<<dim3(2, 32), 256, 0, stream>>>(
        mkargs(deter_new, DET, DET, nullptr, 0, Wo + (size_t)E_DIM * HID, HID, DET, 128, 32, Pb));
    k_fin<<<16, 1024, 0, stream>>>(Pb, 32, out + (size_t)t * OUT_C + 5120, OUT_RSTRIDE,
                                   go, bo, h2);
    // post-sample GEMM: h2 @ Wob
    k_gemm<true><<<dim3(2, 16), 256, 0, stream>>>(
        mkargs(h2, HID, HID, nullptr, 0, Wob, SD, HID, 64, 16, Ps1));
    k_samp<<<16, 1024, 0, stream>>>(
        Ps1, 16, bbo, gpost + (size_t)t * SD, (long)T_STEPS * SD,
        out + (size_t)t * OUT_C + 0, OUT_RSTRIDE,
        out + (size_t)t * OUT_C + 5120, OUT_RSTRIDE,
        isf, pa, t, stoch_in, a_eff, init_stoch);
  }

  // ---- deferred prior branch (batched over all (b,t)) ----
  k_mm<<<dim3(16, 16), 256, 0, stream>>>(out + 1024, OUT_C, W2a, DET, h_all, HID, nullptr);
  k_ln_rows<<<1024, 256, 0, stream>>>(h_all, g2, b2);
  k_mm<<<dim3(16, 16), 256, 0, stream>>>(h_all, HID, W2b, HID, out + 7168, OUT_C, bb2);
  k_samp_prior<<<1024, 1024, 0, stream>>>(out, gprior);
}